// Round 4
// baseline (3666.206 us; speedup 1.0000x reference)
//
#include <hip/hip_runtime.h>

// WordGenerator: bidirectional LSTM (H=256) + 3 stacked LSTM cells (H2=512) + vocab proj.
// Round 4: ALL float tensors are FLOAT32 (per reference dtype — rounds 1-3 read them as
// bf16, whose mantissa halves decode as bf16-NaN ~0.4%/elem => the deterministic NaN).
//  * f32 operands split on-the-fly into hi+lo bf16; products via 3 MFMAs
//    (AhBh + AhBl + AlBh; lo*lo dropped, rel err 2^-18) -> f32-faithful GEMMs.
//  * Rings & c-states f32 (no recurrent rounding). Output f32.
//  * 131 step kernels; step s runs fwd[t=s], bwd[t=s], L1[s-1], L2[s-2], L3[s-3]
//    (stream order = pipeline sync). Rings depth 4.
//  * WG = 64 batch rows x 16 h-cols, owning the 4 matching gate cols (i,f,g,o);
//    cell update lane-local (C/D: col=lane&15 -> gate col, row=(lane>>4)*4+reg -> batch).
//  * Scratch: 512 KiB h3-final copy always in d_ws; 10.5 MiB big region in d_ws if it
//    fits, else front of d_out (fully overwritten by k_out afterwards).

typedef __bf16 bf16x8 __attribute__((ext_vector_type(8)));
typedef float f32x4 __attribute__((ext_vector_type(4)));

__device__ __forceinline__ float sigm(float x) { return 1.0f / (1.0f + expf(-x)); }

// split 8 f32 into hi/lo bf16x8
__device__ __forceinline__ void split8(const f32x4& a0, const f32x4& a1, bf16x8& h,
                                       bf16x8& l) {
#pragma unroll
  for (int j = 0; j < 4; ++j) {
    float f = a0[j];
    __bf16 hb = (__bf16)f;
    h[j] = hb;
    l[j] = (__bf16)(f - (float)hb);
  }
#pragma unroll
  for (int j = 0; j < 4; ++j) {
    float f = a1[j];
    __bf16 hb = (__bf16)f;
    h[4 + j] = hb;
    l[4 + j] = (__bf16)(f - (float)hb);
  }
}

// -------------------- c-state init (f32 copy; inputs are pristine/read-only) ----------
__global__ __launch_bounds__(256) void k_init(const float* c0f, const float* c0b,
                                              const float* c01, const float* c02,
                                              const float* c03, float* cf, float* cb,
                                              float* c1, float* c2, float* c3) {
  const int i = blockIdx.x * 256 + threadIdx.x;  // 524288 total
  if (i < 65536) cf[i] = c0f[i];
  else if (i < 131072) cb[i - 65536] = c0b[i - 65536];
  else if (i < 262144) c1[i - 131072] = c01[i - 131072];
  else if (i < 393216) c2[i - 262144] = c02[i - 262144];
  else c3[i - 393216] = c03[i - 393216];
}

// -------------------- one LSTM-cell tile (f32 in, f32 state/out) --------------------
// gates[64 x 4*16] = A(64 x Kx) @ Wih^T + H(64 x Hc) @ Whh^T for (m0, j0);
// arow/hrow/wihrow/whhrow are per-STAGING-THREAD row pointers (srow = tid>>2).
template <int Kx, int Hc>
__device__ __forceinline__ void cell_core(const float* __restrict__ arow,
                                          const float* __restrict__ hrow,
                                          const float* __restrict__ wihrow,
                                          const float* __restrict__ whhrow,
                                          const float* __restrict__ bih,
                                          const float* __restrict__ bhh,
                                          float* __restrict__ cst,
                                          float* __restrict__ ho, int ldho, int m0,
                                          int j0, __bf16* lAh, __bf16* lAl,
                                          __bf16* lBh, __bf16* lBl) {
  const int tid = threadIdx.x, lane = tid & 63, wv = tid >> 6;
  const int mr = lane & 15, qk = (lane >> 4) * 8;
  const int srow = tid >> 2, scq = (tid & 3) * 8;  // staging: 64 rows x 32 cols
  constexpr int NX = Kx / 32, NT = NX + Hc / 32;

  auto gA = [&](int k, f32x4& x0, f32x4& x1) {
    const float* p = (k < NX) ? arow + k * 32 + scq : hrow + (k - NX) * 32 + scq;
    x0 = *(const f32x4*)p;
    x1 = *(const f32x4*)(p + 4);
  };
  auto gB = [&](int k, f32x4& x0, f32x4& x1) {
    const float* p = (k < NX) ? wihrow + k * 32 + scq : whhrow + (k - NX) * 32 + scq;
    x0 = *(const f32x4*)p;
    x1 = *(const f32x4*)(p + 4);
  };

  f32x4 acc[4] = {};
  f32x4 a0, a1, b0, b1;
  gA(0, a0, a1);
  gB(0, b0, b1);
  for (int k = 0; k < NT; ++k) {
    __syncthreads();
    bf16x8 hh, ll;
    split8(a0, a1, hh, ll);
    *(bf16x8*)(lAh + srow * 40 + scq) = hh;  // stride 40: 16B-aligned, <=2-way bank
    *(bf16x8*)(lAl + srow * 40 + scq) = ll;
    split8(b0, b1, hh, ll);
    *(bf16x8*)(lBh + srow * 40 + scq) = hh;
    *(bf16x8*)(lBl + srow * 40 + scq) = ll;
    if (k + 1 < NT) { gA(k + 1, a0, a1); gB(k + 1, b0, b1); }  // prefetch over MFMA
    __syncthreads();
    bf16x8 ah = *(const bf16x8*)(lAh + (wv * 16 + mr) * 40 + qk);
    bf16x8 al = *(const bf16x8*)(lAl + (wv * 16 + mr) * 40 + qk);
#pragma unroll
    for (int G = 0; G < 4; ++G) {
      bf16x8 bh = *(const bf16x8*)(lBh + (G * 16 + mr) * 40 + qk);
      bf16x8 bl = *(const bf16x8*)(lBl + (G * 16 + mr) * 40 + qk);
      acc[G] = __builtin_amdgcn_mfma_f32_16x16x32_bf16(ah, bh, acc[G], 0, 0, 0);
      acc[G] = __builtin_amdgcn_mfma_f32_16x16x32_bf16(ah, bl, acc[G], 0, 0, 0);
      acc[G] = __builtin_amdgcn_mfma_f32_16x16x32_bf16(al, bh, acc[G], 0, 0, 0);
    }
  }

  const int jc = j0 + mr, r0 = (lane >> 4) * 4;
  float bs[4];
#pragma unroll
  for (int G = 0; G < 4; ++G) bs[G] = bih[G * Hc + jc] + bhh[G * Hc + jc];
#pragma unroll
  for (int r = 0; r < 4; ++r) {
    const int brow = m0 + wv * 16 + r0 + r;
    const size_t ci = (size_t)brow * Hc + jc;
    const float gi = acc[0][r] + bs[0];
    const float gf = acc[1][r] + bs[1];
    const float gg = acc[2][r] + bs[2];
    const float go = acc[3][r] + bs[3];
    const float cn = sigm(gf) * cst[ci] + sigm(gi) * tanhf(gg);
    const float hn = sigm(go) * tanhf(cn);
    cst[ci] = cn;
    ho[(size_t)brow * ldho + jc] = hn;
  }
}

// -------------------- pipelined step kernel --------------------
struct P {
  const int* x;
  const float* emb;
  float *pairs, *h1a, *h2a, *h3a;  // ring-4 slices of (256 x 512) f32
  float *cf, *cb, *c1, *c2, *c3;
  const float *Wihf, *Whhf, *bihf, *bhhf;
  const float *Wihb, *Whhb, *bihb, *bhhb;
  const float *W1ih, *W1hh, *b1ih, *b1hh;
  const float *W2ih, *W2hh, *b2ih, *b2hh;
  const float *W3ih, *W3hh, *b3ih, *b3hh;
  const float *h0f, *h0b, *h01, *h02, *h03;
};

__global__ __launch_bounds__(256) void k_step(P p, int s) {
  __shared__ __align__(16) __bf16 lAh[64 * 40];
  __shared__ __align__(16) __bf16 lAl[64 * 40];
  __shared__ __align__(16) __bf16 lBh[64 * 40];
  __shared__ __align__(16) __bf16 lBl[64 * 40];
  const int wg = blockIdx.x;  // 0-63 fwd, 64-127 bwd, 128-255 L1, 256-383 L2, 384-511 L3
  const int srow = threadIdx.x >> 2;
  const int RING = 256 * 512;
  if (wg < 128) {
    const int dir = wg >> 6, widx = wg & 63, t = s;
    if (t >= 128) return;
    const int m0 = (widx >> 4) * 64, j0 = (widx & 15) * 16;
    const int wrow = (srow >> 4) * 256 + j0 + (srow & 15);  // gate-major weight row
    const int tok = p.x[(dir == 0 ? t : 127 - t) * 256 + m0 + srow];
    const float* arow = p.emb + (size_t)tok * 256;
    const float* hrow =
        (t == 0) ? (dir == 0 ? p.h0f : p.h0b) + (size_t)(m0 + srow) * 256
                 : p.pairs + ((t - 1) & 3) * RING + (dir ? 256 : 0) +
                       (size_t)(m0 + srow) * 512;
    const float* Wih = dir ? p.Wihb : p.Wihf;
    const float* Whh = dir ? p.Whhb : p.Whhf;
    const float* bih = dir ? p.bihb : p.bihf;
    const float* bhh = dir ? p.bhhb : p.bhhf;
    float* ho = p.pairs + (t & 3) * RING + (dir ? 256 : 0);
    cell_core<256, 256>(arow, hrow, Wih + (size_t)wrow * 256, Whh + (size_t)wrow * 256,
                        bih, bhh, dir ? p.cb : p.cf, ho, 512, m0, j0, lAh, lAl, lBh,
                        lBl);
  } else {
    const int st = (wg - 128) >> 7;  // 0,1,2 -> L1,L2,L3
    const int widx = (wg - 128) & 127;
    const int t = s - 1 - st;  // pipeline skew
    if (t < 0 || t >= 128) return;
    const int m0 = (widx >> 5) * 64, j0 = (widx & 31) * 16;
    const int wrow = (srow >> 4) * 512 + j0 + (srow & 15);
    const int ring = (t & 3) * RING, ringp = ((t - 1) & 3) * RING;
    const float *xin, *hp, *Wih, *Whh, *bih, *bhh;
    float *cst, *ho;
    if (st == 0) {
      xin = p.pairs + ring;
      hp = (t == 0) ? p.h01 : p.h1a + ringp;
      Wih = p.W1ih; Whh = p.W1hh; bih = p.b1ih; bhh = p.b1hh;
      cst = p.c1; ho = p.h1a + ring;
    } else if (st == 1) {
      xin = p.h1a + ring;
      hp = (t == 0) ? p.h02 : p.h2a + ringp;
      Wih = p.W2ih; Whh = p.W2hh; bih = p.b2ih; bhh = p.b2hh;
      cst = p.c2; ho = p.h2a + ring;
    } else {
      xin = p.h2a + ring;
      hp = (t == 0) ? p.h03 : p.h3a + ringp;
      Wih = p.W3ih; Whh = p.W3hh; bih = p.b3ih; bhh = p.b3hh;
      cst = p.c3; ho = p.h3a + ring;
    }
    cell_core<512, 512>(xin + (size_t)(m0 + srow) * 512, hp + (size_t)(m0 + srow) * 512,
                        Wih + (size_t)wrow * 512, Whh + (size_t)wrow * 512, bih, bhh,
                        cst, ho, 512, m0, j0, lAh, lAl, lBh, lBl);
  }
}

// -------------------- copy final h3 (ring slot 3) into the safe ws region ------------
__global__ __launch_bounds__(256) void k_copy(const float* __restrict__ src,
                                              float* __restrict__ dst) {
  const int i = blockIdx.x * 256 + threadIdx.x;  // 131072
  dst[i] = src[i];
}

// -------------------- output projection: out = h3 @ Wout^T + bout (f32) -------------
__global__ __launch_bounds__(256) void k_out(const float* __restrict__ h3,
                                             const float* __restrict__ Wt,
                                             const float* __restrict__ bo,
                                             float* __restrict__ out) {
  __shared__ __align__(16) __bf16 sAh[64 * 40];
  __shared__ __align__(16) __bf16 sAl[64 * 40];
  __shared__ __align__(16) __bf16 sBh[64 * 40];
  __shared__ __align__(16) __bf16 sBl[64 * 40];
  const int tid = threadIdx.x, lane = tid & 63, wv = tid >> 6;
  const int mr = lane & 15, qk = (lane >> 4) * 8;
  const int mt = blockIdx.x & 3, n0 = (blockIdx.x >> 2) * 64;
  const int srow = tid >> 2, scq = (tid & 3) * 8;
  const int m0 = mt * 64;
  int wr = n0 + srow;
  if (wr > 50256) wr = 50256;  // clamp loads, mask stores
  f32x4 acc[4] = {};
  f32x4 a0 = *(const f32x4*)(h3 + (size_t)(m0 + srow) * 512 + scq);
  f32x4 a1 = *(const f32x4*)(h3 + (size_t)(m0 + srow) * 512 + scq + 4);
  f32x4 b0 = *(const f32x4*)(Wt + (size_t)wr * 512 + scq);
  f32x4 b1 = *(const f32x4*)(Wt + (size_t)wr * 512 + scq + 4);
  for (int k = 0; k < 16; ++k) {
    __syncthreads();
    bf16x8 hh, ll;
    split8(a0, a1, hh, ll);
    *(bf16x8*)(sAh + srow * 40 + scq) = hh;
    *(bf16x8*)(sAl + srow * 40 + scq) = ll;
    split8(b0, b1, hh, ll);
    *(bf16x8*)(sBh + srow * 40 + scq) = hh;
    *(bf16x8*)(sBl + srow * 40 + scq) = ll;
    if (k < 15) {
      const int kk = (k + 1) * 32;
      a0 = *(const f32x4*)(h3 + (size_t)(m0 + srow) * 512 + kk + scq);
      a1 = *(const f32x4*)(h3 + (size_t)(m0 + srow) * 512 + kk + scq + 4);
      b0 = *(const f32x4*)(Wt + (size_t)wr * 512 + kk + scq);
      b1 = *(const f32x4*)(Wt + (size_t)wr * 512 + kk + scq + 4);
    }
    __syncthreads();
    bf16x8 ah = *(const bf16x8*)(sAh + (wv * 16 + mr) * 40 + qk);
    bf16x8 al = *(const bf16x8*)(sAl + (wv * 16 + mr) * 40 + qk);
#pragma unroll
    for (int G = 0; G < 4; ++G) {
      bf16x8 bh = *(const bf16x8*)(sBh + (G * 16 + mr) * 40 + qk);
      bf16x8 bl = *(const bf16x8*)(sBl + (G * 16 + mr) * 40 + qk);
      acc[G] = __builtin_amdgcn_mfma_f32_16x16x32_bf16(ah, bh, acc[G], 0, 0, 0);
      acc[G] = __builtin_amdgcn_mfma_f32_16x16x32_bf16(ah, bl, acc[G], 0, 0, 0);
      acc[G] = __builtin_amdgcn_mfma_f32_16x16x32_bf16(al, bh, acc[G], 0, 0, 0);
    }
  }
  const int r0 = (lane >> 4) * 4;
#pragma unroll
  for (int G = 0; G < 4; ++G) {
    const int n = n0 + G * 16 + mr;
    if (n < 50257) {
      const float bv = bo[n];
#pragma unroll
      for (int r = 0; r < 4; ++r) {
        const int brow = m0 + wv * 16 + r0 + r;
        out[(size_t)brow * 50257 + n] = acc[G][r] + bv;
      }
    }
  }
}

// -------------------- host --------------------
extern "C" void kernel_launch(void* const* d_in, const int* in_sizes, int n_in,
                              void* d_out, int out_size, void* d_ws, size_t ws_size,
                              hipStream_t stream) {
  (void)in_sizes; (void)n_in; (void)out_size;

  // small always-in-ws region: final h3 copy (512 KiB) — all k_out reads besides d_in
  char* wsp = (char*)d_ws;
  float* h3c = (float*)wsp;

  // big scratch (10.5 MiB): f32 rings + c-states; ws if it fits, else front of d_out
  const size_t SMALL = 1ull << 19, BIG = 11ull << 20;
  char* w = (ws_size >= SMALL + BIG + (1ull << 20)) ? wsp + SMALL : (char*)d_out;
  auto take = [&](size_t bytes) {
    char* r = w;
    w += (bytes + 255) & ~(size_t)255;
    return r;
  };
  float* pairs = (float*)take(4ull * 256 * 512 * 4);  // 2 MiB each ring
  float* h1a = (float*)take(4ull * 256 * 512 * 4);
  float* h2a = (float*)take(4ull * 256 * 512 * 4);
  float* h3a = (float*)take(4ull * 256 * 512 * 4);
  float* cf = (float*)take(256ull * 256 * 4);
  float* cb = (float*)take(256ull * 256 * 4);
  float* c1 = (float*)take(256ull * 512 * 4);
  float* c2 = (float*)take(256ull * 512 * 4);
  float* c3 = (float*)take(256ull * 512 * 4);

  P p;
  p.x = (const int*)d_in[0];
  p.emb = (const float*)d_in[1];
  p.pairs = pairs; p.h1a = h1a; p.h2a = h2a; p.h3a = h3a;
  p.cf = cf; p.cb = cb; p.c1 = c1; p.c2 = c2; p.c3 = c3;
  p.Wihf = (const float*)d_in[2];  p.Whhf = (const float*)d_in[3];
  p.bihf = (const float*)d_in[4];  p.bhhf = (const float*)d_in[5];
  p.Wihb = (const float*)d_in[6];  p.Whhb = (const float*)d_in[7];
  p.bihb = (const float*)d_in[8];  p.bhhb = (const float*)d_in[9];
  p.W1ih = (const float*)d_in[10]; p.W1hh = (const float*)d_in[11];
  p.b1ih = (const float*)d_in[12]; p.b1hh = (const float*)d_in[13];
  p.W2ih = (const float*)d_in[14]; p.W2hh = (const float*)d_in[15];
  p.b2ih = (const float*)d_in[16]; p.b2hh = (const float*)d_in[17];
  p.W3ih = (const float*)d_in[18]; p.W3hh = (const float*)d_in[19];
  p.b3ih = (const float*)d_in[20]; p.b3hh = (const float*)d_in[21];
  const float* Wout = (const float*)d_in[22];
  const float* bout = (const float*)d_in[23];
  p.h0f = (const float*)d_in[24]; p.h0b = (const float*)d_in[26];
  p.h01 = (const float*)d_in[28]; p.h02 = (const float*)d_in[30];
  p.h03 = (const float*)d_in[32];

  k_init<<<dim3(2048), dim3(256), 0, stream>>>(
      (const float*)d_in[25], (const float*)d_in[27], (const float*)d_in[29],
      (const float*)d_in[31], (const float*)d_in[33], cf, cb, c1, c2, c3);

  for (int s = 0; s < 131; ++s)
    k_step<<<dim3(512), dim3(256), 0, stream>>>(p, s);

  // final h3 (t=127 -> ring slot 3) into ws, then the vocab projection
  k_copy<<<dim3(512), dim3(256), 0, stream>>>(h3a + 3 * (256 * 512), h3c);
  k_out<<<dim3(3144), dim3(256), 0, stream>>>(h3c, Wout, bout, (float*)d_out);
}